// Round 7
// baseline (703.986 us; speedup 1.0000x reference)
//
#include <hip/hip_runtime.h>

constexpr int T = 168;
constexpr int P = 16;
constexpr int H = 24;
constexpr int R = 4;      // batch rows per wave

__device__ __forceinline__ float rcp_f(float x) { return __builtin_amdgcn_rcpf(x); }
__device__ __forceinline__ float sigm_f(float x) { return rcp_f(1.f + __expf(-x)); }
// tanh(x) = 2*sigmoid(2x) - 1
__device__ __forceinline__ float tanh_fast(float x) {
    return fmaf(2.f, rcp_f(1.f + __expf(-2.f * x)), -1.f);
}
// Compiler scheduling fence only (no lgkmcnt drain): same-wave DS ops execute
// in order in the LDS pipe, so intra-wave RAW through LDS needs no hardware
// wait — and s_load (SMEM, also lgkmcnt) prefetches survive across the fence.
#define WAVE_FENCE() __builtin_amdgcn_wave_barrier()

// One wave per workgroup, FOUR batch rows per wave, 1024 waves = 1/SIMD.
// waves_per_eu(1,1): register budget 512 -> the 176 weight floats + temps
// (~240) fit in ARCH VGPRs (<=256), removing the AGPR-parking tax seen in
// R2-R4 (VGPR_Count stuck at 76-124). Rows are interleaved inside each K-quad
// so each weight value is fetched once per 4 rows (tax/4 if parking persists)
// and 8 independent accumulator chains hide FMA latency at 1 wave/SIMD.
// x is read via wave-uniform scalar loads (SGPR operand -> zero LDS traffic).
__global__ __attribute__((amdgpu_flat_work_group_size(64, 64),
                          amdgpu_waves_per_eu(1, 1)))
void lstm2_w4(const float* __restrict__ x,
              const float* __restrict__ Wih1, const float* __restrict__ Whh1,
              const float* __restrict__ bih1, const float* __restrict__ bhh1,
              const float* __restrict__ Wih2, const float* __restrict__ Whh2,
              const float* __restrict__ bih2, const float* __restrict__ bhh2,
              const float* __restrict__ W1, const float* __restrict__ b1,
              const float* __restrict__ W2, const float* __restrict__ b2,
              float* __restrict__ out)
{
    const int lane = threadIdx.x;                 // 0..63
    const int s    = (lane < 48) ? lane : 47;     // clamp idle lanes
    const int u    = s % H;                       // unit 0..23
    const int half = s / H;                       // 0: {i,g}, 1: {f,o}
    const int q0   = half * H + u;                // i or f gate row
    const int q1   = (2 + half) * H + u;          // g or o gate row
    const int row0 = blockIdx.x * R;

    // ---- weights into registers: 176 floats ----
    float wx0[P], wx1[P];         // Wih1 rows q0, q1
    float wh0[H], wh1[H];         // Whh1 rows q0, q1
    float vx0[H], vx1[H];         // Wih2 rows q0, q1
    float vh0[H], vh1[H];         // Whh2 rows q0, q1
    #pragma unroll
    for (int k = 0; k < P / 4; ++k) {
        float4 a = ((const float4*)(Wih1 + q0 * P))[k];
        float4 b = ((const float4*)(Wih1 + q1 * P))[k];
        wx0[4*k] = a.x; wx0[4*k+1] = a.y; wx0[4*k+2] = a.z; wx0[4*k+3] = a.w;
        wx1[4*k] = b.x; wx1[4*k+1] = b.y; wx1[4*k+2] = b.z; wx1[4*k+3] = b.w;
    }
    #pragma unroll
    for (int k = 0; k < H / 4; ++k) {
        float4 a = ((const float4*)(Whh1 + q0 * H))[k];
        float4 b = ((const float4*)(Whh1 + q1 * H))[k];
        wh0[4*k] = a.x; wh0[4*k+1] = a.y; wh0[4*k+2] = a.z; wh0[4*k+3] = a.w;
        wh1[4*k] = b.x; wh1[4*k+1] = b.y; wh1[4*k+2] = b.z; wh1[4*k+3] = b.w;
    }
    #pragma unroll
    for (int k = 0; k < H / 4; ++k) {
        float4 a = ((const float4*)(Wih2 + q0 * H))[k];
        float4 b = ((const float4*)(Wih2 + q1 * H))[k];
        vx0[4*k] = a.x; vx0[4*k+1] = a.y; vx0[4*k+2] = a.z; vx0[4*k+3] = a.w;
        vx1[4*k] = b.x; vx1[4*k+1] = b.y; vx1[4*k+2] = b.z; vx1[4*k+3] = b.w;
    }
    #pragma unroll
    for (int k = 0; k < H / 4; ++k) {
        float4 a = ((const float4*)(Whh2 + q0 * H))[k];
        float4 b = ((const float4*)(Whh2 + q1 * H))[k];
        vh0[4*k] = a.x; vh0[4*k+1] = a.y; vh0[4*k+2] = a.z; vh0[4*k+3] = a.w;
        vh1[4*k] = b.x; vh1[4*k+1] = b.y; vh1[4*k+2] = b.z; vh1[4*k+3] = b.w;
    }
    const float b10 = bih1[q0] + bhh1[q0];
    const float b11 = bih1[q1] + bhh1[q1];
    const float b20 = bih2[q0] + bhh2[q0];
    const float b21 = bih2[q1] + bhh2[q1];

    __shared__ __align__(16) float h1s[R][32];
    __shared__ __align__(16) float t1s[R][32];
    __shared__ __align__(16) float h2s[R][32];

    if (lane < H) {
        #pragma unroll
        for (int r = 0; r < R; ++r) { h1s[r][lane] = 0.f; h2s[r][lane] = 0.f; }
    }
    WAVE_FENCE();

    float c1[R], c2[R];
    #pragma unroll
    for (int r = 0; r < R; ++r) { c1[r] = 0.f; c2[r] = 0.f; }

    for (int t = 0; t < T; ++t) {
        // ================= layer 1, all rows interleaved =================
        float g0[R], g1[R];
        #pragma unroll
        for (int r = 0; r < R; ++r) { g0[r] = b10; g1[r] = b11; }
        // x-part: wave-uniform addresses -> s_load; SGPR operand, zero LDS
        #pragma unroll
        for (int r = 0; r < R; ++r) {
            const float* xp = x + ((size_t)(row0 + r) * T + t) * P;
            #pragma unroll
            for (int k = 0; k < P; ++k) {
                float xv = xp[k];
                g0[r] = fmaf(xv, wx0[k], g0[r]);
                g1[r] = fmaf(xv, wx1[k], g1[r]);
            }
        }
        // h-part: per K-quad, fetch weights once, apply to all 4 rows
        #pragma unroll
        for (int k = 0; k < H / 4; ++k) {
            float4 hv[R];
            #pragma unroll
            for (int r = 0; r < R; ++r) hv[r] = ((const float4*)h1s[r])[k];
            #pragma unroll
            for (int r = 0; r < R; ++r) {
                g0[r] = fmaf(hv[r].x, wh0[4*k],   g0[r]);  g1[r] = fmaf(hv[r].x, wh1[4*k],   g1[r]);
                g0[r] = fmaf(hv[r].y, wh0[4*k+1], g0[r]);  g1[r] = fmaf(hv[r].y, wh1[4*k+1], g1[r]);
                g0[r] = fmaf(hv[r].z, wh0[4*k+2], g0[r]);  g1[r] = fmaf(hv[r].z, wh1[4*k+2], g1[r]);
                g0[r] = fmaf(hv[r].w, wh0[4*k+3], g0[r]);  g1[r] = fmaf(hv[r].w, wh1[4*k+3], g1[r]);
            }
        }
        #pragma unroll
        for (int r = 0; r < R; ++r) {
            float a0 = sigm_f(g0[r]);                      // i (half0) | f (half1)
            float px = (half == 0) ? g1[r] + g1[r] : g1[r];
            float sv = sigm_f(px);
            float a1 = (half == 0) ? sv + sv - 1.f : sv;   // tanh(g) | o
            float fa = __shfl(a0, lane + 24);
            float oa = __shfl(a1, lane + 24);
            c1[r] = fmaf(fa, c1[r], a0 * a1);
            float hv = oa * tanh_fast(c1[r]);
            float th = tanh_fast(hv);
            if (lane < H) { h1s[r][lane] = hv; t1s[r][lane] = th; }
        }
        WAVE_FENCE();

        // ================= layer 2, all rows interleaved =================
        float g2[R], g3[R];
        #pragma unroll
        for (int r = 0; r < R; ++r) { g2[r] = b20; g3[r] = b21; }
        #pragma unroll
        for (int k = 0; k < H / 4; ++k) {
            float4 tv[R];
            #pragma unroll
            for (int r = 0; r < R; ++r) tv[r] = ((const float4*)t1s[r])[k];
            #pragma unroll
            for (int r = 0; r < R; ++r) {
                g2[r] = fmaf(tv[r].x, vx0[4*k],   g2[r]);  g3[r] = fmaf(tv[r].x, vx1[4*k],   g3[r]);
                g2[r] = fmaf(tv[r].y, vx0[4*k+1], g2[r]);  g3[r] = fmaf(tv[r].y, vx1[4*k+1], g3[r]);
                g2[r] = fmaf(tv[r].z, vx0[4*k+2], g2[r]);  g3[r] = fmaf(tv[r].z, vx1[4*k+2], g3[r]);
                g2[r] = fmaf(tv[r].w, vx0[4*k+3], g2[r]);  g3[r] = fmaf(tv[r].w, vx1[4*k+3], g3[r]);
            }
        }
        #pragma unroll
        for (int k = 0; k < H / 4; ++k) {
            float4 hv[R];
            #pragma unroll
            for (int r = 0; r < R; ++r) hv[r] = ((const float4*)h2s[r])[k];
            #pragma unroll
            for (int r = 0; r < R; ++r) {
                g2[r] = fmaf(hv[r].x, vh0[4*k],   g2[r]);  g3[r] = fmaf(hv[r].x, vh1[4*k],   g3[r]);
                g2[r] = fmaf(hv[r].y, vh0[4*k+1], g2[r]);  g3[r] = fmaf(hv[r].y, vh1[4*k+1], g3[r]);
                g2[r] = fmaf(hv[r].z, vh0[4*k+2], g2[r]);  g3[r] = fmaf(hv[r].z, vh1[4*k+2], g3[r]);
                g2[r] = fmaf(hv[r].w, vh0[4*k+3], g2[r]);  g3[r] = fmaf(hv[r].w, vh1[4*k+3], g3[r]);
            }
        }
        #pragma unroll
        for (int r = 0; r < R; ++r) {
            float a2 = sigm_f(g2[r]);
            float py = (half == 0) ? g3[r] + g3[r] : g3[r];
            float sw = sigm_f(py);
            float a3 = (half == 0) ? sw + sw - 1.f : sw;
            float fb = __shfl(a2, lane + 24);
            float ob = __shfl(a3, lane + 24);
            c2[r] = fmaf(fb, c2[r], a2 * a3);
            if (lane < H) h2s[r][lane] = ob * tanh_fast(c2[r]);
        }
        WAVE_FENCE();
    }

    // ---- head: tanh -> fc1(16, relu) -> fc2(24), all rows ----
    if (lane < H) {
        #pragma unroll
        for (int r = 0; r < R; ++r) t1s[r][lane] = tanh_fast(h2s[r][lane]);
    }
    WAVE_FENCE();
    if (lane < 16) {
        #pragma unroll
        for (int r = 0; r < R; ++r) {
            float acc = b1[lane];
            #pragma unroll
            for (int j = 0; j < H; ++j) acc = fmaf(t1s[r][j], W1[lane * H + j], acc);
            h1s[r][lane] = fmaxf(acc, 0.f);
        }
    }
    WAVE_FENCE();
    if (lane < H) {
        #pragma unroll
        for (int r = 0; r < R; ++r) {
            float acc = b2[lane];
            #pragma unroll
            for (int j = 0; j < 16; ++j) acc = fmaf(h1s[r][j], W2[lane * 16 + j], acc);
            out[(size_t)(row0 + r) * H + lane] = acc;
        }
    }
}

extern "C" void kernel_launch(void* const* d_in, const int* in_sizes, int n_in,
                              void* d_out, int out_size, void* d_ws, size_t ws_size,
                              hipStream_t stream)
{
    const float* x    = (const float*)d_in[0];
    const float* Wih1 = (const float*)d_in[1];
    const float* Whh1 = (const float*)d_in[2];
    const float* bih1 = (const float*)d_in[3];
    const float* bhh1 = (const float*)d_in[4];
    const float* Wih2 = (const float*)d_in[5];
    const float* Whh2 = (const float*)d_in[6];
    const float* bih2 = (const float*)d_in[7];
    const float* bhh2 = (const float*)d_in[8];
    const float* W1   = (const float*)d_in[9];
    const float* b1   = (const float*)d_in[10];
    const float* W2   = (const float*)d_in[11];
    const float* b2   = (const float*)d_in[12];
    float* out = (float*)d_out;

    const int B = in_sizes[0] / (T * P);             // 4096
    hipLaunchKernelGGL(lstm2_w4, dim3(B / R), dim3(64), 0, stream,
                       x, Wih1, Whh1, bih1, bhh1, Wih2, Whh2, bih2, bhh2,
                       W1, b1, W2, b2, out);
}

// Round 8
// 389.372 us; speedup vs baseline: 1.8080x; 1.8080x over previous
//
#include <hip/hip_runtime.h>

constexpr int T = 168;
constexpr int P = 16;
constexpr int H = 24;

typedef float v2f __attribute__((ext_vector_type(2)));

__device__ __forceinline__ v2f mk2(float a, float b) { v2f r; r[0] = a; r[1] = b; return r; }
__device__ __forceinline__ v2f bc2(float a)          { v2f r; r[0] = a; r[1] = a; return r; }
// 2 fp32 FMAs in one instruction (v_pk_fma_f32) — the only path to the
// 157 TF fp32 rate; plain v_fma_f32 caps at ~half (m07).
__device__ __forceinline__ v2f pkfma(v2f a, v2f b, v2f c) {
    return __builtin_elementwise_fma(a, b, c);
}

__device__ __forceinline__ float rcp_f(float x) { return __builtin_amdgcn_rcpf(x); }
__device__ __forceinline__ float sigm_f(float x) { return rcp_f(1.f + __expf(-x)); }
// tanh(x) = 2*sigmoid(2x) - 1
__device__ __forceinline__ float tanh_fast(float x) {
    return fmaf(2.f, rcp_f(1.f + __expf(-2.f * x)), -1.f);
}

#define KEEP2(v) asm volatile("" : "+v"(v))
// Intra-wave LDS write->read ordering + compiler reorder fence.
#define LDS_SYNC() asm volatile("s_waitcnt lgkmcnt(0)" ::: "memory")

// R4 structure (best measured: 2 rows/wave, 2 waves/SIMD, zero barriers) with
// all gate FMAs converted to packed fp32. Lane u in [0,24): gates {i,g} of
// unit u; lane 24+u: gates {f,o}; lanes 48..63 idle. Weights are float2 pairs
// {row q0, row q1}; one v_pk_fma_f32 replaces two v_fma_f32.
// R7 lesson: never drop below 2 waves/SIMD — latency hiding beats the
// register-parking tax. waves_per_eu(2,2) as in R4.
__global__ __attribute__((amdgpu_flat_work_group_size(64, 64),
                          amdgpu_waves_per_eu(2, 2)))
void lstm2_pk(const float* __restrict__ x,
              const float* __restrict__ Wih1, const float* __restrict__ Whh1,
              const float* __restrict__ bih1, const float* __restrict__ bhh1,
              const float* __restrict__ Wih2, const float* __restrict__ Whh2,
              const float* __restrict__ bih2, const float* __restrict__ bhh2,
              const float* __restrict__ W1, const float* __restrict__ b1,
              const float* __restrict__ W2, const float* __restrict__ b2,
              float* __restrict__ out)
{
    const int lane = threadIdx.x;                 // 0..63
    const int s    = (lane < 48) ? lane : 47;     // clamp idle lanes
    const int u    = s % H;                       // unit 0..23
    const int half = s / H;                       // 0: {i,g}, 1: {f,o}
    const int q0   = half * H + u;                // i or f gate row
    const int q1   = (2 + half) * H + u;          // g or o gate row
    const int rowA = blockIdx.x * 2;
    const int rowB = rowA + 1;

    // ---- weights as packed pairs: 88 v2f = 176 floats ----
    v2f wx[P];   // Wih1 {q0,q1}
    v2f wh[H];   // Whh1 {q0,q1}
    v2f vx[H];   // Wih2 {q0,q1}
    v2f vh[H];   // Whh2 {q0,q1}
    #pragma unroll
    for (int k = 0; k < P; ++k) wx[k] = mk2(Wih1[q0 * P + k], Wih1[q1 * P + k]);
    #pragma unroll
    for (int k = 0; k < H; ++k) wh[k] = mk2(Whh1[q0 * H + k], Whh1[q1 * H + k]);
    #pragma unroll
    for (int k = 0; k < H; ++k) vx[k] = mk2(Wih2[q0 * H + k], Wih2[q1 * H + k]);
    #pragma unroll
    for (int k = 0; k < H; ++k) vh[k] = mk2(Whh2[q0 * H + k], Whh2[q1 * H + k]);
    v2f bias1 = mk2(bih1[q0] + bhh1[q0], bih1[q1] + bhh1[q1]);
    v2f bias2 = mk2(bih2[q0] + bhh2[q0], bih2[q1] + bhh2[q1]);

    #pragma unroll
    for (int k = 0; k < P; ++k) KEEP2(wx[k]);
    #pragma unroll
    for (int k = 0; k < H; ++k) { KEEP2(wh[k]); KEEP2(vx[k]); KEEP2(vh[k]); }
    KEEP2(bias1); KEEP2(bias2);

    __shared__ __align__(16) float h1s[2][32];   // layer-1 h, per row
    __shared__ __align__(16) float t1s[2][32];   // tanh(h1) = layer-2 input
    __shared__ __align__(16) float h2s[2][32];   // layer-2 h

    if (lane < H) {
        h1s[0][lane] = 0.f; t1s[0][lane] = 0.f; h2s[0][lane] = 0.f;
        h1s[1][lane] = 0.f; t1s[1][lane] = 0.f; h2s[1][lane] = 0.f;
    }
    LDS_SYNC();

    const float* __restrict__ xA = x + (size_t)rowA * T * P;  // wave-uniform
    const float* __restrict__ xB = x + (size_t)rowB * T * P;  // wave-uniform

    float c1A = 0.f, c2A = 0.f, c1B = 0.f, c2B = 0.f;

    for (int t = 0; t < T; ++t) {
        // ===== layer 1, rows A and B (independent chains, packed gates) =====
        v2f gA = bias1, gB = bias1;
        #pragma unroll
        for (int k = 0; k < P; ++k) {
            gA = pkfma(bc2(xA[t * P + k]), wx[k], gA);
            gB = pkfma(bc2(xB[t * P + k]), wx[k], gB);
        }
        #pragma unroll
        for (int k = 0; k < H / 4; ++k) {
            float4 ha = ((const float4*)h1s[0])[k];
            float4 hb = ((const float4*)h1s[1])[k];
            gA = pkfma(bc2(ha.x), wh[4*k],   gA);  gB = pkfma(bc2(hb.x), wh[4*k],   gB);
            gA = pkfma(bc2(ha.y), wh[4*k+1], gA);  gB = pkfma(bc2(hb.y), wh[4*k+1], gB);
            gA = pkfma(bc2(ha.z), wh[4*k+2], gA);  gB = pkfma(bc2(hb.z), wh[4*k+2], gB);
            gA = pkfma(bc2(ha.w), wh[4*k+3], gA);  gB = pkfma(bc2(hb.w), wh[4*k+3], gB);
        }
        {
            float a0 = sigm_f(gA[0]);                       // i (half0) | f (half1)
            float px = (half == 0) ? gA[1] + gA[1] : gA[1];
            float sv = sigm_f(px);
            float a1 = (half == 0) ? sv + sv - 1.f : sv;    // tanh(g) | o
            float fa = __shfl(a0, lane + 24);
            float oa = __shfl(a1, lane + 24);
            c1A = fmaf(fa, c1A, a0 * a1);
            float hv = oa * tanh_fast(c1A);
            float th = tanh_fast(hv);
            if (lane < H) { h1s[0][lane] = hv; t1s[0][lane] = th; }
        }
        {
            float a0 = sigm_f(gB[0]);
            float px = (half == 0) ? gB[1] + gB[1] : gB[1];
            float sv = sigm_f(px);
            float a1 = (half == 0) ? sv + sv - 1.f : sv;
            float fa = __shfl(a0, lane + 24);
            float oa = __shfl(a1, lane + 24);
            c1B = fmaf(fa, c1B, a0 * a1);
            float hv = oa * tanh_fast(c1B);
            float th = tanh_fast(hv);
            if (lane < H) { h1s[1][lane] = hv; t1s[1][lane] = th; }
        }
        LDS_SYNC();

        // ===== layer 2, rows A and B (packed) =====
        v2f fA = bias2, fB = bias2;
        #pragma unroll
        for (int k = 0; k < H / 4; ++k) {
            float4 ta = ((const float4*)t1s[0])[k];
            float4 tb = ((const float4*)t1s[1])[k];
            fA = pkfma(bc2(ta.x), vx[4*k],   fA);  fB = pkfma(bc2(tb.x), vx[4*k],   fB);
            fA = pkfma(bc2(ta.y), vx[4*k+1], fA);  fB = pkfma(bc2(tb.y), vx[4*k+1], fB);
            fA = pkfma(bc2(ta.z), vx[4*k+2], fA);  fB = pkfma(bc2(tb.z), vx[4*k+2], fB);
            fA = pkfma(bc2(ta.w), vx[4*k+3], fA);  fB = pkfma(bc2(tb.w), vx[4*k+3], fB);
        }
        #pragma unroll
        for (int k = 0; k < H / 4; ++k) {
            float4 ha = ((const float4*)h2s[0])[k];
            float4 hb = ((const float4*)h2s[1])[k];
            fA = pkfma(bc2(ha.x), vh[4*k],   fA);  fB = pkfma(bc2(hb.x), vh[4*k],   fB);
            fA = pkfma(bc2(ha.y), vh[4*k+1], fA);  fB = pkfma(bc2(hb.y), vh[4*k+1], fB);
            fA = pkfma(bc2(ha.z), vh[4*k+2], fA);  fB = pkfma(bc2(hb.z), vh[4*k+2], fB);
            fA = pkfma(bc2(ha.w), vh[4*k+3], fA);  fB = pkfma(bc2(hb.w), vh[4*k+3], fB);
        }
        {
            float a2 = sigm_f(fA[0]);
            float py = (half == 0) ? fA[1] + fA[1] : fA[1];
            float sw = sigm_f(py);
            float a3 = (half == 0) ? sw + sw - 1.f : sw;
            float fb = __shfl(a2, lane + 24);
            float ob = __shfl(a3, lane + 24);
            c2A = fmaf(fb, c2A, a2 * a3);
            if (lane < H) h2s[0][lane] = ob * tanh_fast(c2A);
        }
        {
            float a2 = sigm_f(fB[0]);
            float py = (half == 0) ? fB[1] + fB[1] : fB[1];
            float sw = sigm_f(py);
            float a3 = (half == 0) ? sw + sw - 1.f : sw;
            float fb = __shfl(a2, lane + 24);
            float ob = __shfl(a3, lane + 24);
            c2B = fmaf(fb, c2B, a2 * a3);
            if (lane < H) h2s[1][lane] = ob * tanh_fast(c2B);
        }
        LDS_SYNC();
    }

    // ---- head: tanh -> fc1(16, relu) -> fc2(24), both rows ----
    if (lane < H) {
        t1s[0][lane] = tanh_fast(h2s[0][lane]);
        t1s[1][lane] = tanh_fast(h2s[1][lane]);
    }
    LDS_SYNC();
    if (lane < 16) {
        float accA = b1[lane], accB = b1[lane];
        #pragma unroll
        for (int j = 0; j < H; ++j) {
            float w = W1[lane * H + j];
            accA = fmaf(t1s[0][j], w, accA);
            accB = fmaf(t1s[1][j], w, accB);
        }
        h1s[0][lane] = fmaxf(accA, 0.f);
        h1s[1][lane] = fmaxf(accB, 0.f);
    }
    LDS_SYNC();
    if (lane < H) {
        float accA = b2[lane], accB = b2[lane];
        #pragma unroll
        for (int j = 0; j < 16; ++j) {
            float w = W2[lane * 16 + j];
            accA = fmaf(h1s[0][j], w, accA);
            accB = fmaf(h1s[1][j], w, accB);
        }
        out[(size_t)rowA * H + lane] = accA;
        out[(size_t)rowB * H + lane] = accB;
    }
}

extern "C" void kernel_launch(void* const* d_in, const int* in_sizes, int n_in,
                              void* d_out, int out_size, void* d_ws, size_t ws_size,
                              hipStream_t stream)
{
    const float* x    = (const float*)d_in[0];
    const float* Wih1 = (const float*)d_in[1];
    const float* Whh1 = (const float*)d_in[2];
    const float* bih1 = (const float*)d_in[3];
    const float* bhh1 = (const float*)d_in[4];
    const float* Wih2 = (const float*)d_in[5];
    const float* Whh2 = (const float*)d_in[6];
    const float* bih2 = (const float*)d_in[7];
    const float* bhh2 = (const float*)d_in[8];
    const float* W1   = (const float*)d_in[9];
    const float* b1   = (const float*)d_in[10];
    const float* W2   = (const float*)d_in[11];
    const float* b2   = (const float*)d_in[12];
    float* out = (float*)d_out;

    const int B = in_sizes[0] / (T * P);             // 4096
    hipLaunchKernelGGL(lstm2_pk, dim3(B / 2), dim3(64), 0, stream,
                       x, Wih1, Whh1, bih1, bhh1, Wih2, Whh2, bih2, bhh2,
                       W1, b1, W2, b2, out);
}